// Round 1
// baseline (275.307 us; speedup 1.0000x reference)
//
#include <hip/hip_runtime.h>
#include <math.h>

#define BB 512
#define TT 1024
#define NS 50

typedef _Float16 half2_t __attribute__((ext_vector_type(2)));

static __device__ __forceinline__ half2_t pk_h2(float a, float b) {
    auto r = __builtin_amdgcn_cvt_pkrtz(a, b);   // packs (a -> lo, b -> hi)
    return __builtin_bit_cast(half2_t, r);
}
static __device__ __forceinline__ float wave_sum_f(float v) {
    #pragma unroll
    for (int k = 32; k >= 1; k >>= 1) v += __shfl_xor(v, k, 64);
    return v;
}
static __device__ __forceinline__ int wave_sum_i(int v) {
    #pragma unroll
    for (int k = 32; k >= 1; k >>= 1) v += __shfl_xor(v, k, 64);
    return v;
}
#define FDOT(a, b, c) __builtin_amdgcn_fdot2((a), (b), (c), false)

__global__ __launch_bounds__(128, 1) void crf_nll_kernel(
    const float* __restrict__ feat,    // (B, T, N)
    const float* __restrict__ trans,   // (N, N)
    const int*   __restrict__ tags,    // (B, T)
    const int*   __restrict__ mask,    // (B, T)
    float* __restrict__ out)           // (B,)
{
    const int b    = blockIdx.x;
    const int tid  = threadIdx.x;
    const int w    = tid >> 6;        // wave 0 = forward, wave 1 = backward (zeta)
    const int lane = tid & 63;
    const int jj   = (lane < NS) ? lane : 0;

    __shared__ float sh_comb[64];
    __shared__ float sh_sc[2];
    __shared__ int   sh_Kb;

    // --- E fragments as 25 named packed-f16 regs (register-resident).
    // fwd: e_m = (E[2m][j], E[2m+1][j]);  bwd: e_m = (E[j][2m], E[j][2m+1])
    // exp(-10000) == 0 exactly -> forbidden transitions vanish.
#define INIT_E(m) half2_t e##m; { \
        int r0 = w ? (jj * NS + 2*(m)) : ((2*(m)) * NS + jj); \
        int r1 = r0 + (w ? 1 : NS); \
        float x0 = __expf(trans[r0]); \
        float x1 = __expf(trans[r1]); \
        if (lane >= NS) { x0 = 0.f; x1 = 0.f; } \
        e##m = pk_h2(x0, x1); }
    INIT_E(0)  INIT_E(1)  INIT_E(2)  INIT_E(3)  INIT_E(4)
    INIT_E(5)  INIT_E(6)  INIT_E(7)  INIT_E(8)  INIT_E(9)
    INIT_E(10) INIT_E(11) INIT_E(12) INIT_E(13) INIT_E(14)
    INIT_E(15) INIT_E(16) INIT_E(17) INIT_E(18) INIT_E(19)
    INIT_E(20) INIT_E(21) INIT_E(22) INIT_E(23) INIT_E(24)
#undef INIT_E

    // --- sequence length (mask is a prefix of ones); uniform ---
    int cnt = 0;
    for (int t = lane; t < TT; t += 64) cnt += mask[b * TT + t];
    const int len = wave_sum_i(cnt);
    const int tm  = (len - 1) >> 1;          // cut point
    const int nst = w ? (len - 1 - tm) : tm; // steps this wave runs

    const float* fb = feat + (size_t)b * TT * NS;

    // --- prob-domain init: fwd u=exp(alpha0); bwd u=exp(zeta_{len-1}), zeta=beta+feat
    float u;
    if (w == 0) u = (lane < NS) ? __expf(trans[jj] + fb[jj]) : 0.f;
    else        u = (lane < NS) ? __expf(trans[jj * NS + 1] + fb[(size_t)(len - 1) * NS + jj]) : 0.f;
    int K = 0, kp, rr;
    { int bb2 = __builtin_amdgcn_readlane(__float_as_int(u), 7);
      kp = ((bb2 >> 23) & 255) - 127; rr = (127 - kp) << 23; }

    // --- one step. eexp = exp(feat row value), precomputed off-chain. ---
    // Broadcast of the 25 packed state-pairs is done with v_readlane -> SGPR
    // (no LDS round trip). Even lane 2m holds pack(u[2m], u[2m+1]); odd lanes
    // hold the swapped pair but are never read.
    auto step = [&](float eexp) {
        K += kp;
        float p = u * __int_as_float(rr);             // lane7 in [1,2); others e^±spread
        int pn_ = __builtin_amdgcn_update_dpp(
            __float_as_int(p), __float_as_int(p), 0xB1, 0xF, 0xF, true); // lane^1
        float pnf = __int_as_float(pn_);
        half2_t pk = pk_h2(p, pnf);                   // even lane: (u[2m], u[2m+1])
        int pki = __builtin_bit_cast(int, pk);
        float s0 = 0.f, s1 = 0.f, s2 = 0.f, s3 = 0.f;
        float s4 = 0.f, s5 = 0.f, s6 = 0.f, s7 = 0.f;
#define RLF(m, acc) { int b_ = __builtin_amdgcn_readlane(pki, 2*(m)); \
        acc = FDOT(__builtin_bit_cast(half2_t, b_), e##m, acc); }
        RLF(0,  s0) RLF(1,  s1) RLF(2,  s2) RLF(3,  s3)
        RLF(4,  s4) RLF(5,  s5) RLF(6,  s6) RLF(7,  s7)
        RLF(8,  s0) RLF(9,  s1) RLF(10, s2) RLF(11, s3)
        RLF(12, s4) RLF(13, s5) RLF(14, s6) RLF(15, s7)
        RLF(16, s0) RLF(17, s1) RLF(18, s2) RLF(19, s3)
        RLF(20, s4) RLF(21, s5) RLF(22, s6) RLF(23, s7)
        RLF(24, s0)
#undef RLF
        float S = ((s0 + s1) + (s2 + s3)) + ((s4 + s5) + (s6 + s7));
        u = S * eexp;                                  // dead lanes: e==0 -> u stays 0
        int bb2 = __builtin_amdgcn_readlane(__float_as_int(u), 7);  // lane7 never dead
        kp = ((bb2 >> 23) & 255) - 127;
        rr = (127 - kp) << 23;
    };

    // --- depth-8 prefetch, PRE-EXP'D (exp off critical chain), unrolled x8 ---
    float q0, q1, q2, q3, q4, q5, q6, q7;
    {
        int t0 = w ? (len - 2) : 1;
        int st = w ? -1 : 1;
#define LD(qr, d) { int tl = t0 + st * (d); tl = (tl < 0) ? 0 : ((tl < TT) ? tl : TT - 1); \
                    qr = __expf(fb[(size_t)tl * NS + jj]); }
        LD(q0, 0) LD(q1, 1) LD(q2, 2) LD(q3, 3) LD(q4, 4) LD(q5, 5) LD(q6, 6) LD(q7, 7)
#undef LD
    }

#define PF_STEP(qr, d) { \
        float e_ = qr; \
        int kl = k + 8 + (d); \
        int tl = w ? (len - 2 - kl) : (1 + kl); \
        tl = (tl < 0) ? 0 : ((tl < TT) ? tl : TT - 1); \
        qr = __expf(fb[(size_t)tl * NS + jj]); \
        step(e_); }

    int k = 0;
    for (; k + 8 <= nst; k += 8) {
        PF_STEP(q0, 0) PF_STEP(q1, 1) PF_STEP(q2, 2) PF_STEP(q3, 3)
        PF_STEP(q4, 4) PF_STEP(q5, 5) PF_STEP(q6, 6) PF_STEP(q7, 7)
    }
#undef PF_STEP
    for (; k < nst; ++k) {                    // tail <8 steps, rows L1-hot
        int tl = w ? (len - 2 - k) : (1 + k);
        step(__expf(fb[(size_t)tl * NS + jj]));
    }

    // --- bwd publishes ub*exp(-feat[tm]) (= exp(beta[tm]) scaled) and Kb ---
    if (w == 1) {
        sh_comb[lane] = u * __expf(-fb[(size_t)tm * NS + jj]);  // 0 for dead lanes
        if (lane == 0) sh_Kb = K;
    }

    // --- gold path score (exact, log-domain): both waves, stride-128 over t ---
    const int* tb = tags + (size_t)b * TT;
    float sc = 0.0f;
    for (int t2 = tid; t2 < len; t2 += 128) {
        int tg = tb[t2];
        sc += fb[(size_t)t2 * NS + tg];
        if (t2 >= 1) sc += trans[tb[t2 - 1] * NS + tg];
    }
    sc = wave_sum_f(sc);
    if (lane == 0) sh_sc[w] = sc;

    __syncthreads();

    if (w == 0) {
        // log_z = ln( sum_j uf_j * ub_j * exp(-feat[tm][j]) ) + (Kf+Kb)*ln2
        float wv = u * sh_comb[lane];         // dead lanes contribute 0
        float W = wave_sum_f(wv);
        float log_z = __logf(W) + (float)(K + sh_Kb) * 0.6931471805599453f;
        if (lane == 0) {
            float sct = sh_sc[0] + sh_sc[1]
                      + trans[tb[0]]                      // trans[ROOT][tag0]
                      + trans[tb[len - 1] * NS + 1];      // trans[tag_last][END]
            out[b] = log_z - sct;
        }
    }
}

extern "C" void kernel_launch(void* const* d_in, const int* in_sizes, int n_in,
                              void* d_out, int out_size, void* d_ws, size_t ws_size,
                              hipStream_t stream) {
    const float* feat  = (const float*)d_in[0];
    const float* trans = (const float*)d_in[1];
    const int*   tags  = (const int*)d_in[2];
    const int*   mask  = (const int*)d_in[3];
    float* out = (float*)d_out;
    crf_nll_kernel<<<dim3(BB), dim3(128), 0, stream>>>(feat, trans, tags, mask, out);
}